// Round 3
// baseline (199.202 us; speedup 1.0000x reference)
//
#include <hip/hip_runtime.h>
#include <math.h>

// Problem constants: B=32, S=2048, D=1024, H=8, D_HEAD=32, D_HEAD_OUT=128
#define S_  2048
#define D_  1024
// M = 65536 rows, GEMM1: [M,1024]@[1024,256]; GEMM2 per-head K=32 -> [M,1024] logits

typedef __attribute__((ext_vector_type(8))) short short8;
typedef __attribute__((ext_vector_type(4))) float f32x4;

static __device__ __forceinline__ unsigned short f2bf(float x) {
    unsigned int u = __builtin_bit_cast(unsigned int, x);
    u += 0x7fffu + ((u >> 16) & 1u);
    return (unsigned short)(u >> 16);
}
static __device__ __forceinline__ float bf2f(unsigned short s) {
    unsigned int u = ((unsigned int)s) << 16;
    return __builtin_bit_cast(float, u);
}

__device__ __forceinline__ void gl_lds16(const void* g, void* l) {
    __builtin_amdgcn_global_load_lds(
        (const __attribute__((address_space(1))) unsigned int*)g,
        (__attribute__((address_space(3))) unsigned int*)l, 16, 0, 0);
}

// ---------------------------------------------------------------------------
// Pack w1 (fp32 [8][1024][32]) into MFMA B-fragment order, bf16:
//   w1p[((ks*16 + cf)*64 + lane)*8 + r];  col=cf*16+(lane&15) (=h*32+e),
//   k = ks*32 + (lane>>4)*8 + r (= d)
__global__ void prep_w1(const float* __restrict__ w1, short* __restrict__ w1p) {
    int tid = blockIdx.x * 256 + threadIdx.x;   // 32768 threads
    int lane = tid & 63;
    int fragid = tid >> 6;
    int cf = fragid & 15, ks = fragid >> 4;
    int col = cf * 16 + (lane & 15);
    int h = col >> 5, e = col & 31;
    int d0 = ks * 32 + (lane >> 4) * 8;
    short8 v;
#pragma unroll
    for (int r = 0; r < 8; ++r)
        v[r] = (short)f2bf(w1[((size_t)h * D_ + (d0 + r)) * 32 + e]);
    *(short8*)(w1p + (size_t)tid * 8) = v;
}

// Pack w2 (fp32 [8][32][128]) into B-fragment order, bf16:
//   w2p[((h*8 + cf2)*64 + lane)*8 + r]; col=o=cf2*16+(lane&15), k=e=(lane>>4)*8+r
__global__ void prep_w2(const float* __restrict__ w2, short* __restrict__ w2p) {
    int tid = blockIdx.x * 256 + threadIdx.x;   // 4096 threads
    int lane = tid & 63;
    int fragid = tid >> 6;
    int cf2 = fragid & 7, h = fragid >> 3;
    int o = cf2 * 16 + (lane & 15);
    int e0 = (lane >> 4) * 8;
    short8 v;
#pragma unroll
    for (int r = 0; r < 8; ++r)
        v[r] = (short)f2bf(w2[((size_t)h * 32 + (e0 + r)) * 128 + o]);
    *(short8*)(w2p + (size_t)tid * 8) = v;
}

// ---------------------------------------------------------------------------
// Fused: GEMM1 -> gelu -> GEMM2 -> exp -> per-column {sum E, sum feat*E}
// partials for this 64-row group.
// Block = 256 threads (4 waves), 64 rows. GEMM1 wave grid 2x2:
// wave (wr,wc) owns rows wr*32+[0,32), cols wc*128+[0,128).
// GEMM1 pipeline: 3 LDS B-buffers, staged 2 ksteps ahead, counted vmcnt(8)
// + raw s_barrier (loads from kstep k-2 retired; k-1's stay in flight).
__global__ __launch_bounds__(256, 3) void fused1(
        const float* __restrict__ feat,
        const short* __restrict__ w1p,
        const short* __restrict__ w2p,
        const float* __restrict__ b1,
        const float* __restrict__ b2,
        float* __restrict__ pnum,
        float* __restrict__ pden)
{
    __shared__ __align__(16) char lds[49152];
    short* Bbuf = (short*)lds;                       // [3][8192] shorts (3x16KB)
    short* hact16 = (short*)lds;                     // [16][264] bf16 (8448 B)
    unsigned short* Est = (unsigned short*)(lds + 8448);  // [16][1032] bf16 (33024 B)

    const int tid = threadIdx.x;
    const int wv = tid >> 6;
    const int lane = tid & 63;
    const int lr = lane & 15;
    const int lg = lane >> 4;
    const int wr = wv >> 1, wc = wv & 1;
    const size_t m0 = (size_t)blockIdx.x * 64;

    const f32x4* Arow0 = (const f32x4*)(feat + (m0 + (size_t)(wr * 32 + lr)) * D_);
    const f32x4* Arow1 = (const f32x4*)(feat + (m0 + (size_t)(wr * 32 + 16 + lr)) * D_);

    const f32x4 vzero = {0.f, 0.f, 0.f, 0.f};
    f32x4 acc[2][8];
#pragma unroll
    for (int i = 0; i < 2; ++i)
#pragma unroll
        for (int j = 0; j < 8; ++j) acc[i][j] = vzero;

    auto stageB = [&](int buf_, int ks_) {
#pragma unroll
        for (int j = 0; j < 4; ++j)
            gl_lds16(w1p + (size_t)ks_ * 8192 + (size_t)(j * 256 + tid) * 8,
                     Bbuf + buf_ * 8192 + (j * 256 + wv * 64) * 8);
    };
    f32x4 pfA[4], pfB[4];
    auto loadA = [&](f32x4* pf, int ks_) {
        const int o = ks_ * 8 + lg * 2;
        pf[0] = Arow0[o]; pf[1] = Arow0[o + 1];
        pf[2] = Arow1[o]; pf[3] = Arow1[o + 1];
    };
    auto mkfrag = [&](const f32x4* pf, short8& af0, short8& af1) {
        af0[0] = (short)f2bf(pf[0].x); af0[1] = (short)f2bf(pf[0].y);
        af0[2] = (short)f2bf(pf[0].z); af0[3] = (short)f2bf(pf[0].w);
        af0[4] = (short)f2bf(pf[1].x); af0[5] = (short)f2bf(pf[1].y);
        af0[6] = (short)f2bf(pf[1].z); af0[7] = (short)f2bf(pf[1].w);
        af1[0] = (short)f2bf(pf[2].x); af1[1] = (short)f2bf(pf[2].y);
        af1[2] = (short)f2bf(pf[2].z); af1[3] = (short)f2bf(pf[2].w);
        af1[4] = (short)f2bf(pf[3].x); af1[5] = (short)f2bf(pf[3].y);
        af1[6] = (short)f2bf(pf[3].z); af1[7] = (short)f2bf(pf[3].w);
    };
    auto kcompute = [&](int bufI, const short8& af0, const short8& af1) {
        const short8* Bf = (const short8*)(Bbuf + bufI * 8192);
#pragma unroll
        for (int cf = 0; cf < 8; ++cf) {
            short8 bfr = Bf[(wc * 8 + cf) * 64 + lane];
            acc[0][cf] = __builtin_amdgcn_mfma_f32_16x16x32_bf16(af0, bfr, acc[0][cf], 0, 0, 0);
            acc[1][cf] = __builtin_amdgcn_mfma_f32_16x16x32_bf16(af1, bfr, acc[1][cf], 0, 0, 0);
        }
    };

    // ---- GEMM1: 32 ksteps of K=32 ----
    // prologue: issue, in order, B(0),A(0),B(1),A(1)  -> 16 outstanding vmem
    stageB(0, 0); loadA(pfA, 0);
    stageB(1, 1); loadA(pfB, 1);

    int cur = 0;
    for (int kk = 0; kk < 15; ++kk) {      // ks = 2kk, 2kk+1 : 0..29
        const int ks = kk * 2;
        // entry outstanding (old->new): B(k),A(k),B(k+1),A(k+1) = 16.
        // vmcnt(8) retires B(k)+A(k); k+1's 8 stay in flight across barrier.
        asm volatile("s_waitcnt vmcnt(8)" ::: "memory");
        __builtin_amdgcn_s_barrier();
        {
            int nb = cur + 2; if (nb >= 3) nb -= 3;
            stageB(nb, ks + 2);
            short8 af0, af1; mkfrag(pfA, af0, af1);
            loadA(pfA, ks + 2);
            kcompute(cur, af0, af1);
            cur = (cur == 2) ? 0 : cur + 1;
        }
        asm volatile("s_waitcnt vmcnt(8)" ::: "memory");
        __builtin_amdgcn_s_barrier();
        {
            int nb = cur + 2; if (nb >= 3) nb -= 3;
            stageB(nb, ks + 3);
            short8 af0, af1; mkfrag(pfB, af0, af1);
            loadA(pfB, ks + 3);
            kcompute(cur, af0, af1);
            cur = (cur == 2) ? 0 : cur + 1;
        }
    }
    // ks=30: outstanding = B(30),A(30),B(31),A(31) = 16 -> vmcnt(8)
    asm volatile("s_waitcnt vmcnt(8)" ::: "memory");
    __builtin_amdgcn_s_barrier();
    {
        short8 af0, af1; mkfrag(pfA, af0, af1);
        kcompute(cur, af0, af1);
        cur = (cur == 2) ? 0 : cur + 1;
    }
    // ks=31: only B(31),A(31) left -> full drain
    asm volatile("s_waitcnt vmcnt(0)" ::: "memory");
    __builtin_amdgcn_s_barrier();
    {
        short8 af0, af1; mkfrag(pfB, af0, af1);
        kcompute(cur, af0, af1);
    }
    __syncthreads();     // all Bbuf reads done -> LDS reusable

    // ---- GEMM2 + exp + weighted partials, per 16-row group rf ----
    float bias2[16];
#pragma unroll
    for (int cf = 0; cf < 16; ++cf)
        bias2[cf] = b2[(2 * wv + (cf >> 3)) * 128 + (cf & 7) * 16 + lr];

    const int c0 = tid * 4;                 // this thread's 4 output columns
    f32x4 nacc = vzero, dacc = vzero;

    for (int rf = 0; rf < 4; ++rf) {
        // (a) writer waves (wr == rf>>1) emit gelu(h) rows rf*16..+16 to LDS
        if (wr == (rf >> 1)) {
            const int a = rf & 1;
#pragma unroll
            for (int cf = 0; cf < 8; ++cf) {
                const int col = wc * 128 + cf * 16 + lr;
                const float bias = b1[col];
#pragma unroll
                for (int r = 0; r < 4; ++r) {
                    float x = acc[a][cf][r] + bias;
                    float g = 0.5f * x * (1.0f + erff(x * 0.70710678118654752f));
                    hact16[(lg * 4 + r) * 264 + col] = (short)f2bf(g);
                }
            }
        }
        __syncthreads();

        // (b) GEMM2 (K=32, one MFMA per col-frag) + exp -> Est
        short8 ah0 = *(const short8*)(hact16 + lr * 264 + (2 * wv + 0) * 32 + lg * 8);
        short8 ah1 = *(const short8*)(hact16 + lr * 264 + (2 * wv + 1) * 32 + lg * 8);
#pragma unroll
        for (int cf = 0; cf < 16; ++cf) {
            const int h = 2 * wv + (cf >> 3);
            short8 bw = *(const short8*)(w2p + ((size_t)(h * 8 + (cf & 7)) * 64 + lane) * 8);
            f32x4 c = vzero;
            c = __builtin_amdgcn_mfma_f32_16x16x32_bf16((cf < 8) ? ah0 : ah1, bw, c, 0, 0, 0);
            const int colL = wv * 256 + (cf >> 3) * 128 + (cf & 7) * 16 + lr;
#pragma unroll
            for (int r = 0; r < 4; ++r) {
                float e = __expf(c[r] + bias2[cf]);   // logits tiny: no max-sub
                Est[(lg * 4 + r) * 1032 + colL] = f2bf(e);
            }
        }
        __syncthreads();

        // (c) weighting: coalesced f32x4 feat re-read (L2/L3-hot rows), E from LDS
        const float* fb = feat + (m0 + (size_t)rf * 16) * D_ + c0;
#pragma unroll
        for (int row = 0; row < 16; ++row) {
            f32x4 fv = *(const f32x4*)(fb + (size_t)row * D_);
            unsigned long long ev = *(const unsigned long long*)(Est + row * 1032 + c0);
            f32x4 e;
            e.x = bf2f((unsigned short)(ev));
            e.y = bf2f((unsigned short)(ev >> 16));
            e.z = bf2f((unsigned short)(ev >> 32));
            e.w = bf2f((unsigned short)(ev >> 48));
            dacc += e;
            nacc += fv * e;
        }
        __syncthreads();
    }

    const size_t pb = (size_t)blockIdx.x * 1024 + c0;
    *(f32x4*)(pnum + pb) = nacc;
    *(f32x4*)(pden + pb) = dacc;
}

// ---------------------------------------------------------------------------
// out[b,d] = sum_j pnum[b*32+j][d] / sum_j pden[b*32+j][d]
__global__ __launch_bounds__(256) void finalize2(
        const float* __restrict__ pnum,
        const float* __restrict__ pden,
        float* __restrict__ out)
{
    const int idx = blockIdx.x * 256 + threadIdx.x;   // 32768 = 32*1024
    const int b = idx >> 10;
    const int d = idx & 1023;
    const size_t base = (size_t)b * 32 * 1024 + d;
    float n = 0.f, dn = 0.f;
#pragma unroll 8
    for (int j = 0; j < 32; ++j) {
        n  += pnum[base + (size_t)j * 1024];
        dn += pden[base + (size_t)j * 1024];
    }
    out[idx] = n / dn;
}

// ---------------------------------------------------------------------------
extern "C" void kernel_launch(void* const* d_in, const int* in_sizes, int n_in,
                              void* d_out, int out_size, void* d_ws, size_t ws_size,
                              hipStream_t stream) {
    (void)in_sizes; (void)n_in; (void)out_size; (void)ws_size;
    const float* feat = (const float*)d_in[0];
    const float* w1   = (const float*)d_in[1];
    const float* b1   = (const float*)d_in[2];
    const float* w2   = (const float*)d_in[3];
    const float* b2   = (const float*)d_in[4];
    float* out = (float*)d_out;

    char* ws = (char*)d_ws;
    float* pnum = (float*)ws;                          // 4 MiB (1024*1024 f32)
    float* pden = (float*)(ws + (4ull << 20));         // 4 MiB
    short* w1p  = (short*)(ws + (8ull << 20));         // 512 KiB
    short* w2p  = (short*)(ws + (8ull << 20) + (512ull << 10));  // 64 KiB

    prep_w1<<<128, 256, 0, stream>>>(w1, w1p);
    prep_w2<<<16, 256, 0, stream>>>(w2, w2p);
    fused1<<<1024, 256, 0, stream>>>(feat, w1p, w2p, b1, b2, pnum, pden);
    finalize2<<<128, 256, 0, stream>>>(pnum, pden, out);
}